// Round 6
// baseline (264.704 us; speedup 1.0000x reference)
//
#include <hip/hip_runtime.h>
#include <hip/hip_bf16.h>
#include <stdint.h>

// Problem constants
#define EXP 8
#define DIM 1024
#define SEQL 512
#define BATCH 8
#define OFF_AUX    4194304
#define OFF_MASK   4194305
#define OFF_LOGITS 4194369

typedef __bf16 bf16_t;
typedef bf16_t bf16x8 __attribute__((ext_vector_type(8)));
typedef bf16_t bf16x4 __attribute__((ext_vector_type(4)));
typedef float  f32x4  __attribute__((ext_vector_type(4)));

typedef __attribute__((address_space(1))) void* as1p;
typedef __attribute__((address_space(3))) void* as3p;

__device__ __forceinline__ void glds16(const void* g, void* l) {
  // async global->LDS, 16B per lane; LDS dest = wave-uniform base + lane*16
  __builtin_amdgcn_global_load_lds((as1p)(void*)g, (as3p)l, 16, 0, 0);
}

// ---------------------------------------------------------------------------
// prep_kernel: fused { w1+w2 transpose-cast | x cast | router }.
// Transpose now 64x64 fp32 tiles, LDS [64][68] fp32 = 17.4 KB -> 9 blocks/CU
// (was 34.8 KB / 4 blocks/CU): latency-bound phase, occupancy doubles.
// grid.x = 4096 (transpose) + 512 (x cast) + 1 (router), 256 thr.
// ---------------------------------------------------------------------------
__global__ __launch_bounds__(256) void prep_kernel(
    const float* __restrict__ x, const float* __restrict__ dec,
    const float* __restrict__ rw, const float* __restrict__ rb,
    const float* __restrict__ w1, const float* __restrict__ w2,
    bf16_t* __restrict__ xb, bf16_t* __restrict__ w1t, bf16_t* __restrict__ w2t,
    float* __restrict__ out_aux, float* __restrict__ out_mask,
    float* __restrict__ out_logits, int* __restrict__ idx_ws,
    float* __restrict__ w_ws) {
  __shared__ __align__(16) char smem[64 * 68 * 4];   // 17408 B
  const int bid = blockIdx.x;
  const int t = threadIdx.x;

  if (bid < 4096) {
    // ---- transpose-cast: matrix z (16 mats x 256 tiles), 64k x 64n tile ----
    const int z = bid >> 8;
    const int rem = bid & 255;
    const int k0 = (rem >> 4) * 64, n0 = (rem & 15) * 64;
    const float* src = (z < 8) ? (w1 + (size_t)z * DIM * DIM)
                               : (w2 + (size_t)(z - 8) * DIM * DIM);
    bf16_t* dst = (z < 8) ? (w1t + (size_t)z * DIM * DIM)
                          : (w2t + (size_t)(z - 8) * DIM * DIM);
    float (*tile)[68] = (float (*)[68])smem;   // [k][n-ish], stride 68 dwords
    const int r = t >> 4, c = t & 15;          // wave: 4 rows x 256B contiguous
    float4 v[4];
#pragma unroll
    for (int i = 0; i < 4; ++i)
      v[i] = *(const float4*)(src + (size_t)(k0 + r + 16 * i) * DIM + n0 + c * 4);
#pragma unroll
    for (int i = 0; i < 4; ++i)
      *(float4*)&tile[r + 16 * i][c * 4] = v[i];   // 16B-aligned (68%4==0)
    __syncthreads();
    // read k-contiguous per n; lanes span n=0..63 -> banks 2-way (free)
#pragma unroll
    for (int i2 = 0; i2 < 2; ++i2) {
      const int n = t & 63, kc = (t >> 6) + 4 * i2;
      bf16x8 o;
#pragma unroll
      for (int wd = 0; wd < 8; ++wd) o[wd] = (bf16_t)tile[kc * 8 + wd][n];
      *(bf16x8*)(dst + (size_t)(n0 + n) * DIM + k0 + kc * 8) = o;
    }
  } else if (bid < 4096 + 512) {
    // ---- cast x: 1M float4s over 512 blocks, 8 per thread, batched ----
    const int i0 = (bid - 4096) * 2048 + t;
    float4 v[8];
#pragma unroll
    for (int i = 0; i < 8; ++i) v[i] = ((const float4*)x)[i0 + i * 256];
#pragma unroll
    for (int i = 0; i < 8; ++i) {
      bf16x4 o;
      o[0] = (bf16_t)v[i].x; o[1] = (bf16_t)v[i].y;
      o[2] = (bf16_t)v[i].z; o[3] = (bf16_t)v[i].w;
      ((bf16x4*)xb)[i0 + i * 256] = o;
    }
  } else {
    // ---- router (scratch aliased into smem) ----
    float* part  = (float*)smem;       // 256
    float* lg64  = part + 256;         // 64
    float* probs = lg64 + 64;          // 64
    float* msk   = probs + 64;         // 64
    const int p = t >> 2, seg = t & 3;
    const int b = p >> 3, e = p & 7;
    const float4* dv = (const float4*)(dec + b * DIM + seg * 256);
    const float4* wv = (const float4*)(rw + e * DIM + seg * 256);
    float s = 0.f;
#pragma unroll 8
    for (int i = 0; i < 64; ++i) {
      float4 a = dv[i], c = wv[i];
      s += a.x * c.x + a.y * c.y + a.z * c.z + a.w * c.w;
    }
    part[t] = s;
    __syncthreads();
    if (seg == 0) {
      float l = part[t] + part[t + 1] + part[t + 2] + part[t + 3] + rb[e];
      lg64[p] = l;
      out_logits[p] = l;
    }
    __syncthreads();
    if (t < 8) {
      float l[8];
      float mx = -1e30f;
#pragma unroll
      for (int k = 0; k < 8; ++k) { l[k] = lg64[t * 8 + k]; mx = fmaxf(mx, l[k]); }
      float pe[8];
      float sum = 0.f;
#pragma unroll
      for (int k = 0; k < 8; ++k) { pe[k] = expf(l[k] - mx); sum += pe[k]; }
      float inv = 1.f / sum;
#pragma unroll
      for (int k = 0; k < 8; ++k) { pe[k] *= inv; probs[t * 8 + k] = pe[k]; }
      int i0 = 0;
#pragma unroll
      for (int k = 1; k < 8; ++k) if (pe[k] > pe[i0]) i0 = k;
      int i1 = (i0 == 0) ? 1 : 0;
#pragma unroll
      for (int k = 0; k < 8; ++k) if (k != i0 && pe[k] > pe[i1]) i1 = k;
      float p0 = pe[i0], p1 = pe[i1];
      float invs = 1.f / (p0 + p1);
      idx_ws[t * 2] = i0;
      idx_ws[t * 2 + 1] = i1;
      w_ws[t * 2] = p0 * invs;
      w_ws[t * 2 + 1] = p1 * invs;
#pragma unroll
      for (int k = 0; k < 8; ++k) {
        float m = (k == i0 || k == i1) ? 1.f : 0.f;
        msk[t * 8 + k] = m;
        out_mask[t * 8 + k] = m;
      }
    }
    __syncthreads();
    if (t == 0) {
      float aux = 0.f;
#pragma unroll
      for (int k = 0; k < 8; ++k) {
        float mp = 0.f, mm = 0.f;
#pragma unroll
        for (int bb = 0; bb < 8; ++bb) { mp += probs[bb * 8 + k]; mm += msk[bb * 8 + k]; }
        aux += (mp * 0.125f) * (mm * 0.125f);
      }
      out_aux[0] = 8.f * aux;
    }
  }
}

// ---------------------------------------------------------------------------
// Double-buffered MFMA K-loop, 64x128 tile (r5-proven, used by gemm1).
// ---------------------------------------------------------------------------
__device__ __forceinline__ void kloop_64x128(const bf16_t* __restrict__ A,
                                             const bf16_t* __restrict__ Bt,
                                             char* sA, char* sB, int t,
                                             f32x4 acc[2][4]) {
  const int lane = t & 63;
  const int w = t >> 6, wr = w >> 1, wc = w & 1;
  const int m15 = lane & 15, q = lane >> 4;
  const int rl = t >> 2, cp = (t & 3) ^ (rl & 3);
  const bf16_t* ga  = A  + (size_t)rl * DIM + cp * 8;
  const bf16_t* gb0 = Bt + (size_t)rl * DIM + cp * 8;
  const bf16_t* gb1 = gb0 + (size_t)64 * DIM;

  const char* ra[2];
  const char* rb[4];
#pragma unroll
  for (int i = 0; i < 2; ++i) {
    const int r = wr * 32 + i * 16 + m15;
    ra[i] = sA + r * 64 + ((q ^ (r & 3)) * 16);
  }
#pragma unroll
  for (int j = 0; j < 4; ++j) {
    const int n = wc * 64 + j * 16 + m15;
    rb[j] = sB + n * 64 + ((q ^ (n & 3)) * 16);
  }

  glds16(ga,  sA + t * 16);
  glds16(gb0, sB + t * 16);
  glds16(gb1, sB + 4096 + t * 16);

  for (int kt = 0; kt < 32; ++kt) {
    const int cur = kt & 1;
    __syncthreads();
    if (kt < 31) {
      const int nxt = cur ^ 1;
      const int off = (kt + 1) * 32;
      glds16(ga + off,  sA + nxt * 4096 + t * 16);
      glds16(gb0 + off, sB + nxt * 8192 + t * 16);
      glds16(gb1 + off, sB + nxt * 8192 + 4096 + t * 16);
    }
    bf16x8 af[2], bfr[4];
#pragma unroll
    for (int i = 0; i < 2; ++i) af[i] = *(const bf16x8*)(ra[i] + cur * 4096);
#pragma unroll
    for (int j = 0; j < 4; ++j) bfr[j] = *(const bf16x8*)(rb[j] + cur * 8192);
#pragma unroll
    for (int i = 0; i < 2; ++i)
#pragma unroll
      for (int j = 0; j < 4; ++j)
        acc[i][j] = __builtin_amdgcn_mfma_f32_16x16x32_bf16(af[i], bfr[j], acc[i][j], 0, 0, 0);
  }
}

// ---------------------------------------------------------------------------
// GEMM1: hidden[slot] = topk_w[slot] * relu(x[b] @ w1[e] + b1[e]), bf16.
// grid (8 N, 8 M, 16 slots) = 1024 blocks, 256 thr.  (r5-proven)
// ---------------------------------------------------------------------------
__global__ __launch_bounds__(256) void gemm1_kernel(const bf16_t* __restrict__ xb,
                                                    const bf16_t* __restrict__ w1t,
                                                    const float* __restrict__ b1,
                                                    const int* __restrict__ topk_idx,
                                                    const float* __restrict__ topk_w,
                                                    bf16_t* __restrict__ hidden) {
  __shared__ __align__(16) char smem[24576];
  const int tid = threadIdx.x;
  const int bN = blockIdx.x, bM = blockIdx.y, slot = blockIdx.z;
  const int b = slot >> 1;
  const int e = topk_idx[slot];
  const float gw = topk_w[slot];

  const bf16_t* A  = xb + ((size_t)b * SEQL + bM * 64) * DIM;
  const bf16_t* Bt = w1t + ((size_t)e * DIM + bN * 128) * DIM;

  f32x4 acc[2][4];
#pragma unroll
  for (int i = 0; i < 2; ++i)
#pragma unroll
    for (int j = 0; j < 4; ++j) acc[i][j] = {0.f, 0.f, 0.f, 0.f};

  kloop_64x128(A, Bt, smem, smem + 8192, tid, acc);

  __syncthreads();
  bf16_t* hb = (bf16_t*)smem;            // [64][136] halfwords
  const int lane = tid & 63, w = tid >> 6;
  const int wr = w >> 1, wc = w & 1;
  const int m15 = lane & 15, q = lane >> 4;
  const float* be = b1 + e * DIM;
#pragma unroll
  for (int i = 0; i < 2; ++i)
#pragma unroll
    for (int j = 0; j < 4; ++j) {
      const int colL = wc * 64 + j * 16 + m15;
      const float bias = be[bN * 128 + colL];
#pragma unroll
      for (int r = 0; r < 4; ++r) {
        const int rowL = wr * 32 + i * 16 + q * 4 + r;
        hb[rowL * 136 + colL] = (bf16_t)(gw * fmaxf(acc[i][j][r] + bias, 0.f));
      }
    }
  __syncthreads();
  bf16_t* H = hidden + (size_t)slot * SEQL * DIM + ((size_t)bM * 64) * DIM + bN * 128;
#pragma unroll
  for (int ii = 0; ii < 4; ++ii) {
    const int r = (tid >> 4) + 16 * ii;
    const int c = tid & 15;
    bf16x8 vv = *(const bf16x8*)(hb + r * 136 + c * 8);
    *(bf16x8*)(H + (size_t)r * DIM + c * 8) = vv;
  }
}

// ---------------------------------------------------------------------------
// GEMM2 (direct-global, barrier-free): out[b] = h0s@w2[e0] + h1s@w2[e1] + bias.
// No LDS, no __syncthreads in the K-loop: each wave computes an independent
// 32m x 64n tile, loading A/B fragments straight from global (both K-major,
// 16B/lane; one instr = 16 rows x 64B segments, L1/L2-served).  Compiler is
// free to pipeline loads across MFMAs (unroll 4) -> no vmcnt(0) barrier drain.
// Block 256 thr = 4 waves stacked in m (128m x 64n). grid (16 N, 4 M, 8 b).
// ---------------------------------------------------------------------------
__global__ __launch_bounds__(256) void gemm2_kernel(const bf16_t* __restrict__ hidden,
                                                    const bf16_t* __restrict__ w2t,
                                                    const float* __restrict__ b2,
                                                    const int* __restrict__ topk_idx,
                                                    const float* __restrict__ topk_w,
                                                    float* __restrict__ out) {
  const int tid = threadIdx.x;
  const int lane = tid & 63, w = tid >> 6;
  const int m15 = lane & 15, q = lane >> 4;
  const int bN = blockIdx.x, bM = blockIdx.y, b = blockIdx.z;
  const int row0 = bM * 128 + w * 32;     // wave's m-origin
  const int n0 = bN * 64;
  const int e0 = topk_idx[b * 2], e1 = topk_idx[b * 2 + 1];

  f32x4 acc[2][4];
#pragma unroll
  for (int i = 0; i < 2; ++i)
#pragma unroll
    for (int j = 0; j < 4; ++j) acc[i][j] = {0.f, 0.f, 0.f, 0.f};

#pragma unroll
  for (int g = 0; g < 2; ++g) {
    const int e = (g == 0) ? e0 : e1;
    const bf16_t* A = hidden + ((size_t)(b * 2 + g) * SEQL + row0) * DIM;
    const bf16_t* B = w2t + ((size_t)e * DIM + n0) * DIM;
    const bf16_t* pa[2];
    const bf16_t* pb[4];
#pragma unroll
    for (int i = 0; i < 2; ++i) pa[i] = A + (size_t)(i * 16 + m15) * DIM + q * 8;
#pragma unroll
    for (int j = 0; j < 4; ++j) pb[j] = B + (size_t)(j * 16 + m15) * DIM + q * 8;

#pragma unroll 4
    for (int kt = 0; kt < 32; ++kt) {
      const int off = kt * 32;
      bf16x8 af[2], bfr[4];
#pragma unroll
      for (int i = 0; i < 2; ++i) af[i] = *(const bf16x8*)(pa[i] + off);
#pragma unroll
      for (int j = 0; j < 4; ++j) bfr[j] = *(const bf16x8*)(pb[j] + off);
#pragma unroll
      for (int i = 0; i < 2; ++i)
#pragma unroll
        for (int j = 0; j < 4; ++j)
          acc[i][j] = __builtin_amdgcn_mfma_f32_16x16x32_bf16(af[i], bfr[j], acc[i][j], 0, 0, 0);
    }
  }

  // epilogue: direct fp32 stores (lanes 0-15 = 64B contiguous per (i,j,r))
  const float w0 = topk_w[b * 2], w1v = topk_w[b * 2 + 1];
  const float* be0 = b2 + e0 * DIM;
  const float* be1 = b2 + e1 * DIM;
  float* O = out + (size_t)b * SEQL * DIM;
#pragma unroll
  for (int j = 0; j < 4; ++j) {
    const int col = n0 + j * 16 + m15;
    const float bb = w0 * be0[col] + w1v * be1[col];
#pragma unroll
    for (int i = 0; i < 2; ++i) {
      const int row = row0 + i * 16 + q * 4;
#pragma unroll
      for (int r = 0; r < 4; ++r)
        O[(size_t)(row + r) * DIM + col] = acc[i][j][r] + bb;
    }
  }
}

// ---------------------------------------------------------------------------
extern "C" void kernel_launch(void* const* d_in, const int* in_sizes, int n_in,
                              void* d_out, int out_size, void* d_ws, size_t ws_size,
                              hipStream_t stream) {
  const float* x   = (const float*)d_in[0];
  const float* dec = (const float*)d_in[1];
  const float* rw  = (const float*)d_in[2];
  const float* rb  = (const float*)d_in[3];
  const float* w1  = (const float*)d_in[4];
  const float* w2  = (const float*)d_in[5];
  const float* b1  = (const float*)d_in[6];
  const float* b2  = (const float*)d_in[7];
  float* out = (float*)d_out;

  // ws layout: xb 8MB | w1t 16MB | w2t 16MB | hidden 16MB | router scratch
  char* ws = (char*)d_ws;
  bf16_t* xb   = (bf16_t*)(ws);
  bf16_t* w1t  = (bf16_t*)(ws + (8u << 20));
  bf16_t* w2t  = (bf16_t*)(ws + (24u << 20));
  bf16_t* hid  = (bf16_t*)(ws + (40u << 20));
  int*    idxw = (int*)(ws + (56u << 20));
  float*  ww   = (float*)(ws + (56u << 20) + 64);

  hipLaunchKernelGGL(prep_kernel, dim3(4096 + 512 + 1), dim3(256), 0, stream,
                     x, dec, rw, rb, w1, w2, xb, w1t, w2t,
                     out + OFF_AUX, out + OFF_MASK, out + OFF_LOGITS, idxw, ww);
  hipLaunchKernelGGL(gemm1_kernel, dim3(8, 8, 16), dim3(256), 0, stream,
                     xb, w1t, b1, idxw, ww, hid);
  hipLaunchKernelGGL(gemm2_kernel, dim3(16, 4, 8), dim3(256), 0, stream,
                     hid, w2t, b2, idxw, ww, out);
}

// Round 7
// 219.718 us; speedup vs baseline: 1.2047x; 1.2047x over previous
//
#include <hip/hip_runtime.h>
#include <hip/hip_bf16.h>
#include <stdint.h>

// Problem constants
#define EXP 8
#define DIM 1024
#define SEQL 512
#define BATCH 8
#define OFF_AUX    4194304
#define OFF_MASK   4194305
#define OFF_LOGITS 4194369

typedef __bf16 bf16_t;
typedef bf16_t bf16x8 __attribute__((ext_vector_type(8)));
typedef bf16_t bf16x4 __attribute__((ext_vector_type(4)));
typedef float  f32x4  __attribute__((ext_vector_type(4)));

typedef __attribute__((address_space(1))) void* as1p;
typedef __attribute__((address_space(3))) void* as3p;

__device__ __forceinline__ void glds16(const void* g, void* l) {
  __builtin_amdgcn_global_load_lds((as1p)(void*)g, (as3p)l, 16, 0, 0);
}

// ---------------------------------------------------------------------------
// prep_kernel (r6): fused { w1+w2 transpose-cast 64x64 | x cast | router }.
// grid.x = 4096 + 512 + 1, 256 thr, 17.4 KB LDS.
// ---------------------------------------------------------------------------
__global__ __launch_bounds__(256) void prep_kernel(
    const float* __restrict__ x, const float* __restrict__ dec,
    const float* __restrict__ rw, const float* __restrict__ rb,
    const float* __restrict__ w1, const float* __restrict__ w2,
    bf16_t* __restrict__ xb, bf16_t* __restrict__ w1t, bf16_t* __restrict__ w2t,
    float* __restrict__ out_aux, float* __restrict__ out_mask,
    float* __restrict__ out_logits, int* __restrict__ idx_ws,
    float* __restrict__ w_ws) {
  __shared__ __align__(16) char smem[64 * 68 * 4];
  const int bid = blockIdx.x;
  const int t = threadIdx.x;

  if (bid < 4096) {
    const int z = bid >> 8;
    const int rem = bid & 255;
    const int k0 = (rem >> 4) * 64, n0 = (rem & 15) * 64;
    const float* src = (z < 8) ? (w1 + (size_t)z * DIM * DIM)
                               : (w2 + (size_t)(z - 8) * DIM * DIM);
    bf16_t* dst = (z < 8) ? (w1t + (size_t)z * DIM * DIM)
                          : (w2t + (size_t)(z - 8) * DIM * DIM);
    float (*tile)[68] = (float (*)[68])smem;
    const int r = t >> 4, c = t & 15;
    float4 v[4];
#pragma unroll
    for (int i = 0; i < 4; ++i)
      v[i] = *(const float4*)(src + (size_t)(k0 + r + 16 * i) * DIM + n0 + c * 4);
#pragma unroll
    for (int i = 0; i < 4; ++i)
      *(float4*)&tile[r + 16 * i][c * 4] = v[i];
    __syncthreads();
#pragma unroll
    for (int i2 = 0; i2 < 2; ++i2) {
      const int n = t & 63, kc = (t >> 6) + 4 * i2;
      bf16x8 o;
#pragma unroll
      for (int wd = 0; wd < 8; ++wd) o[wd] = (bf16_t)tile[kc * 8 + wd][n];
      *(bf16x8*)(dst + (size_t)(n0 + n) * DIM + k0 + kc * 8) = o;
    }
  } else if (bid < 4096 + 512) {
    const int i0 = (bid - 4096) * 2048 + t;
    float4 v[8];
#pragma unroll
    for (int i = 0; i < 8; ++i) v[i] = ((const float4*)x)[i0 + i * 256];
#pragma unroll
    for (int i = 0; i < 8; ++i) {
      bf16x4 o;
      o[0] = (bf16_t)v[i].x; o[1] = (bf16_t)v[i].y;
      o[2] = (bf16_t)v[i].z; o[3] = (bf16_t)v[i].w;
      ((bf16x4*)xb)[i0 + i * 256] = o;
    }
  } else {
    float* part  = (float*)smem;
    float* lg64  = part + 256;
    float* probs = lg64 + 64;
    float* msk   = probs + 64;
    const int p = t >> 2, seg = t & 3;
    const int b = p >> 3, e = p & 7;
    const float4* dv = (const float4*)(dec + b * DIM + seg * 256);
    const float4* wv = (const float4*)(rw + e * DIM + seg * 256);
    float s = 0.f;
#pragma unroll 8
    for (int i = 0; i < 64; ++i) {
      float4 a = dv[i], c = wv[i];
      s += a.x * c.x + a.y * c.y + a.z * c.z + a.w * c.w;
    }
    part[t] = s;
    __syncthreads();
    if (seg == 0) {
      float l = part[t] + part[t + 1] + part[t + 2] + part[t + 3] + rb[e];
      lg64[p] = l;
      out_logits[p] = l;
    }
    __syncthreads();
    if (t < 8) {
      float l[8];
      float mx = -1e30f;
#pragma unroll
      for (int k = 0; k < 8; ++k) { l[k] = lg64[t * 8 + k]; mx = fmaxf(mx, l[k]); }
      float pe[8];
      float sum = 0.f;
#pragma unroll
      for (int k = 0; k < 8; ++k) { pe[k] = expf(l[k] - mx); sum += pe[k]; }
      float inv = 1.f / sum;
#pragma unroll
      for (int k = 0; k < 8; ++k) { pe[k] *= inv; probs[t * 8 + k] = pe[k]; }
      int i0 = 0;
#pragma unroll
      for (int k = 1; k < 8; ++k) if (pe[k] > pe[i0]) i0 = k;
      int i1 = (i0 == 0) ? 1 : 0;
#pragma unroll
      for (int k = 0; k < 8; ++k) if (k != i0 && pe[k] > pe[i1]) i1 = k;
      float p0 = pe[i0], p1 = pe[i1];
      float invs = 1.f / (p0 + p1);
      idx_ws[t * 2] = i0;
      idx_ws[t * 2 + 1] = i1;
      w_ws[t * 2] = p0 * invs;
      w_ws[t * 2 + 1] = p1 * invs;
#pragma unroll
      for (int k = 0; k < 8; ++k) {
        float m = (k == i0 || k == i1) ? 1.f : 0.f;
        msk[t * 8 + k] = m;
        out_mask[t * 8 + k] = m;
      }
    }
    __syncthreads();
    if (t == 0) {
      float aux = 0.f;
#pragma unroll
      for (int k = 0; k < 8; ++k) {
        float mp = 0.f, mm = 0.f;
#pragma unroll
        for (int bb = 0; bb < 8; ++bb) { mp += probs[bb * 8 + k]; mm += msk[bb * 8 + k]; }
        aux += (mp * 0.125f) * (mm * 0.125f);
      }
      out_aux[0] = 8.f * aux;
    }
  }
}

// ---------------------------------------------------------------------------
// 512-thread double-buffered K-loop, 128m x 128n tile, BK=32.
// 8 waves = 2(m) x 4(n); wave tile 64m x 32n = 4x2 mfma_f32_16x16x32_bf16.
// Staging: one glds16 issue per operand per kt (512 lanes x 16B = 8KB tile).
// LDS: sA 2x8KB, sB 2x8KB (32 KB). XOR-swizzled 16B chunks per 64B row.
// Traffic: 256KB A + 256KB B per block per kloop (2x reuse vs 64x128).
// ---------------------------------------------------------------------------
__device__ __forceinline__ void kloop512(const bf16_t* __restrict__ A,
                                         const bf16_t* __restrict__ Bt,
                                         char* sA, char* sB, int t,
                                         f32x4 acc[4][2]) {
  const int lane = t & 63;
  const int w = t >> 6;
  const int wm = w & 1, wn = w >> 1;
  const int m15 = lane & 15, q = lane >> 4;
  const int rl = t >> 2, cp = (t & 3) ^ (rl & 3);
  const bf16_t* ga = A  + (size_t)rl * DIM + cp * 8;
  const bf16_t* gb = Bt + (size_t)rl * DIM + cp * 8;

  const char* ra[4];
  const char* rb[2];
#pragma unroll
  for (int i = 0; i < 4; ++i) {
    const int r = wm * 64 + i * 16 + m15;
    ra[i] = sA + r * 64 + ((q ^ (r & 3)) * 16);
  }
#pragma unroll
  for (int j = 0; j < 2; ++j) {
    const int n = wn * 32 + j * 16 + m15;
    rb[j] = sB + n * 64 + ((q ^ (n & 3)) * 16);
  }

  glds16(ga, sA + t * 16);
  glds16(gb, sB + t * 16);

  for (int kt = 0; kt < 32; ++kt) {
    const int cur = kt & 1;
    __syncthreads();
    if (kt < 31) {
      const int nxt = cur ^ 1;
      const int off = (kt + 1) * 32;
      glds16(ga + off, sA + nxt * 8192 + t * 16);
      glds16(gb + off, sB + nxt * 8192 + t * 16);
    }
    bf16x8 af[4], bfr[2];
#pragma unroll
    for (int i = 0; i < 4; ++i) af[i] = *(const bf16x8*)(ra[i] + cur * 8192);
#pragma unroll
    for (int j = 0; j < 2; ++j) bfr[j] = *(const bf16x8*)(rb[j] + cur * 8192);
#pragma unroll
    for (int i = 0; i < 4; ++i)
#pragma unroll
      for (int j = 0; j < 2; ++j)
        acc[i][j] = __builtin_amdgcn_mfma_f32_16x16x32_bf16(af[i], bfr[j], acc[i][j], 0, 0, 0);
  }
}

// ---------------------------------------------------------------------------
// GEMM1: hidden[slot] = topk_w[slot] * relu(x[b] @ w1[e] + b1[e]), bf16.
// grid (8 N, 4 M, 17): z<16 = gemm tiles (512 blocks, 2/CU); z==16 = 32-block
// slice writing out = combined bias (enables gemm2's atomicAdd combine).
// ---------------------------------------------------------------------------
__global__ __launch_bounds__(512, 4) void gemm1_kernel(
    const bf16_t* __restrict__ xb, const bf16_t* __restrict__ w1t,
    const float* __restrict__ b1, const float* __restrict__ b2,
    const int* __restrict__ topk_idx, const float* __restrict__ topk_w,
    bf16_t* __restrict__ hidden, float* __restrict__ out) {
  __shared__ __align__(16) char smem[32768];
  const int tid = threadIdx.x;
  const int bN = blockIdx.x, bM = blockIdx.y, slot = blockIdx.z;

  if (slot == 16) {
    // ---- bias init: out[b, s, :] = w0*b2[e0] + w1*b2[e1] ----
    const int b = bN;                    // 0..7
    const int s0 = bM * 128;             // 0..383 (bM 0..3)
    const float g0 = topk_w[b * 2], g1 = topk_w[b * 2 + 1];
    const float4* be0 = (const float4*)(b2 + topk_idx[b * 2] * DIM);
    const float4* be1 = (const float4*)(b2 + topk_idx[b * 2 + 1] * DIM);
    const int f4 = tid & 255, rr = tid >> 8;
    const float4 v0 = be0[f4], v1 = be1[f4];
    float4 bb;
    bb.x = g0 * v0.x + g1 * v1.x;
    bb.y = g0 * v0.y + g1 * v1.y;
    bb.z = g0 * v0.z + g1 * v1.z;
    bb.w = g0 * v0.w + g1 * v1.w;
    float* O = out + (size_t)b * SEQL * DIM;
#pragma unroll
    for (int k = 0; k < 64; ++k)
      *(float4*)(O + (size_t)(s0 + rr + 2 * k) * DIM + f4 * 4) = bb;
    return;
  }

  const int b = slot >> 1;
  const int e = topk_idx[slot];
  const float gw = topk_w[slot];

  const bf16_t* A  = xb + ((size_t)b * SEQL + bM * 128) * DIM;
  const bf16_t* Bt = w1t + ((size_t)e * DIM + bN * 128) * DIM;

  f32x4 acc[4][2];
#pragma unroll
  for (int i = 0; i < 4; ++i)
#pragma unroll
    for (int j = 0; j < 2; ++j) acc[i][j] = {0.f, 0.f, 0.f, 0.f};

  kloop512(A, Bt, smem, smem + 16384, tid, acc);

  // epilogue: bias+relu+gate+cast, half-tile LDS bounce -> bf16x8 stores.
  // C/D layout: col = lane&15, row = quad*4+reg (m89-verified).
  const int lane = tid & 63, w = tid >> 6;
  const int wm = w & 1, wn = w >> 1;
  const int m15 = lane & 15, q = lane >> 4;
  const float* be = b1 + e * DIM;
  bf16_t* hb = (bf16_t*)smem;            // [64][136] halfwords (17.4 KB)
  bf16_t* H = hidden + (size_t)slot * SEQL * DIM + ((size_t)bM * 128) * DIM + bN * 128;
#pragma unroll
  for (int h = 0; h < 2; ++h) {
    __syncthreads();                     // prev phase reads done
    if (wm == h) {
#pragma unroll
      for (int i = 0; i < 4; ++i)
#pragma unroll
        for (int j = 0; j < 2; ++j) {
          const int colL = wn * 32 + j * 16 + m15;
          const float bias = be[bN * 128 + colL];
#pragma unroll
          for (int r = 0; r < 4; ++r) {
            const int lr = i * 16 + q * 4 + r;
            hb[lr * 136 + colL] = (bf16_t)(gw * fmaxf(acc[i][j][r] + bias, 0.f));
          }
        }
    }
    __syncthreads();
#pragma unroll
    for (int ii = 0; ii < 2; ++ii) {
      const int c2 = tid + 512 * ii;     // 1024 bf16x8 chunks
      const int r = c2 >> 4, c = c2 & 15;
      bf16x8 vv = *(const bf16x8*)(hb + r * 136 + c * 8);
      *(bf16x8*)(H + (size_t)(h * 64 + r) * DIM + c * 8) = vv;
    }
  }
}

// ---------------------------------------------------------------------------
// GEMM2: out += h[slot] @ w2[e_slot]  (hidden pre-scaled by gate; bias
// pre-written by gemm1's init slice).  One expert per block; fp32 atomicAdd
// combine (device-scope, disjoint except the 2 expert contributions).
// grid (8 N, 4 M, 16 slots) = 512 blocks (2/CU), 512 thr, 128x128 tile.
// ---------------------------------------------------------------------------
__global__ __launch_bounds__(512, 4) void gemm2_kernel(
    const bf16_t* __restrict__ hidden, const bf16_t* __restrict__ w2t,
    const int* __restrict__ topk_idx, float* __restrict__ out) {
  __shared__ __align__(16) char smem[32768];
  const int tid = threadIdx.x;
  const int bN = blockIdx.x, bM = blockIdx.y, slot = blockIdx.z;
  const int b = slot >> 1;
  const int e = topk_idx[slot];

  const bf16_t* A  = hidden + ((size_t)slot * SEQL + bM * 128) * DIM;
  const bf16_t* Bt = w2t + ((size_t)e * DIM + bN * 128) * DIM;

  f32x4 acc[4][2];
#pragma unroll
  for (int i = 0; i < 4; ++i)
#pragma unroll
    for (int j = 0; j < 2; ++j) acc[i][j] = {0.f, 0.f, 0.f, 0.f};

  kloop512(A, Bt, smem, smem + 16384, tid, acc);

  const int lane = tid & 63, w = tid >> 6;
  const int wm = w & 1, wn = w >> 1;
  const int m15 = lane & 15, q = lane >> 4;
  float* O = out + (size_t)b * SEQL * DIM;
#pragma unroll
  for (int i = 0; i < 4; ++i) {
    const int row = bM * 128 + wm * 64 + i * 16 + q * 4;
#pragma unroll
    for (int j = 0; j < 2; ++j) {
      const int col = bN * 128 + wn * 32 + j * 16 + m15;
#pragma unroll
      for (int r = 0; r < 4; ++r)
        atomicAdd(&O[(size_t)(row + r) * DIM + col], acc[i][j][r]);
    }
  }
}

// ---------------------------------------------------------------------------
extern "C" void kernel_launch(void* const* d_in, const int* in_sizes, int n_in,
                              void* d_out, int out_size, void* d_ws, size_t ws_size,
                              hipStream_t stream) {
  const float* x   = (const float*)d_in[0];
  const float* dec = (const float*)d_in[1];
  const float* rw  = (const float*)d_in[2];
  const float* rb  = (const float*)d_in[3];
  const float* w1  = (const float*)d_in[4];
  const float* w2  = (const float*)d_in[5];
  const float* b1  = (const float*)d_in[6];
  const float* b2  = (const float*)d_in[7];
  float* out = (float*)d_out;

  // ws layout: xb 8MB | w1t 16MB | w2t 16MB | hidden 16MB | router scratch
  char* ws = (char*)d_ws;
  bf16_t* xb   = (bf16_t*)(ws);
  bf16_t* w1t  = (bf16_t*)(ws + (8u << 20));
  bf16_t* w2t  = (bf16_t*)(ws + (24u << 20));
  bf16_t* hid  = (bf16_t*)(ws + (40u << 20));
  int*    idxw = (int*)(ws + (56u << 20));
  float*  ww   = (float*)(ws + (56u << 20) + 64);

  hipLaunchKernelGGL(prep_kernel, dim3(4096 + 512 + 1), dim3(256), 0, stream,
                     x, dec, rw, rb, w1, w2, xb, w1t, w2t,
                     out + OFF_AUX, out + OFF_MASK, out + OFF_LOGITS, idxw, ww);
  hipLaunchKernelGGL(gemm1_kernel, dim3(8, 4, 17), dim3(512), 0, stream,
                     xb, w1t, b1, b2, idxw, ww, hid, out);
  hipLaunchKernelGGL(gemm2_kernel, dim3(8, 4, 16), dim3(512), 0, stream,
                     hid, w2t, idxw, out);
}